// Round 3
// baseline (274.610 us; speedup 1.0000x reference)
//
#include <hip/hip_runtime.h>
#include <hip/hip_bf16.h>
#include <stdint.h>

#define NTOK 4096
#define DM   512
#define HD   2048
#define NE   8

typedef __bf16 bf16x8 __attribute__((ext_vector_type(8)));
typedef float  f32x4  __attribute__((ext_vector_type(4)));

__device__ __forceinline__ unsigned short f2bf(float f) {
  unsigned int u = __float_as_uint(f);
  u += 0x7FFF + ((u >> 16) & 1);   // RTNE
  return (unsigned short)(u >> 16);
}

__device__ __forceinline__ float gelu_tanh(float x) {
  float u = 0.7978845608028654f * (x + 0.044715f * x * x * x);
  return 0.5f * x * (1.0f + tanhf(u));
}

__device__ __forceinline__ void gload_lds16(const void* g, void* l) {
  __builtin_amdgcn_global_load_lds(
      (__attribute__((address_space(1))) const void*)g,
      (__attribute__((address_space(3))) void*)l,
      16, 0, 0);
}

// ---------- X: fp32 -> bf16 ----------
__global__ __launch_bounds__(256) void convx_kernel(
    const float* __restrict__ in, unsigned short* __restrict__ out, int n8) {
  int i = blockIdx.x * 256 + threadIdx.x;
  if (i >= n8) return;
  const f32x4* p = (const f32x4*)(in + (size_t)i * 8);
  f32x4 v0 = p[0], v1 = p[1];
  union { unsigned short s[8]; uint4 u; } o;
  #pragma unroll
  for (int j = 0; j < 4; j++) { o.s[j] = f2bf(v0[j]); o.s[4 + j] = f2bf(v1[j]); }
  *(uint4*)(out + (size_t)i * 8) = o.u;
}

// ---------- W[e][K][N] fp32 -> WT[e][N][K] bf16 (tiled transpose) ----------
template<int K, int N>
__global__ __launch_bounds__(256) void transw_kernel(
    const float* __restrict__ in, unsigned short* __restrict__ out) {
  __shared__ float tile[32][33];
  const int tpe = (K / 32) * (N / 32);
  int e   = blockIdx.x / tpe;
  int rem = blockIdx.x % tpe;
  int kt  = rem / (N / 32), nt = rem % (N / 32);
  int tx  = threadIdx.x & 31, ty = threadIdx.x >> 5;
  const float* src = in + ((size_t)e * K + kt * 32) * N + (size_t)nt * 32;
  #pragma unroll
  for (int i = 0; i < 4; i++) {
    int r = ty + i * 8;
    tile[r][tx] = src[(size_t)r * N + tx];
  }
  __syncthreads();
  unsigned short* dst = out + ((size_t)e * N + nt * 32) * K + (size_t)kt * 32;
  #pragma unroll
  for (int i = 0; i < 4; i++) {
    int rr = ty + i * 8;
    dst[(size_t)rr * K + tx] = f2bf(tile[tx][rr]);
  }
}

// ---------- gate: fp32 logits, top-2, softmax, build per-expert lists ----------
__global__ __launch_bounds__(256) void gate_kernel(
    const float* __restrict__ inp, const float* __restrict__ gw,
    const float* __restrict__ gb, int* __restrict__ lists,
    int* __restrict__ counts, float* __restrict__ wgtA) {
  int tok = blockIdx.x * 4 + (threadIdx.x >> 6);
  int l   = threadIdx.x & 63;
  const float* x = inp + (size_t)tok * DM;
  float acc[NE];
  #pragma unroll
  for (int e = 0; e < NE; e++) acc[e] = 0.f;
  #pragma unroll
  for (int j = 0; j < DM / 64; j++) {
    int d = j * 64 + l;
    float xv = x[d];
    const float* g = gw + (size_t)d * NE;
    #pragma unroll
    for (int e = 0; e < NE; e++) acc[e] += xv * g[e];
  }
  #pragma unroll
  for (int off = 32; off >= 1; off >>= 1) {
    #pragma unroll
    for (int e = 0; e < NE; e++) acc[e] += __shfl_xor(acc[e], off, 64);
  }
  if (l == 0) {
    float lg[NE];
    #pragma unroll
    for (int e = 0; e < NE; e++) lg[e] = acc[e] + gb[e];
    int i0 = 0;
    #pragma unroll
    for (int e = 1; e < NE; e++) if (lg[e] > lg[i0]) i0 = e;
    int i1 = (i0 == 0) ? 1 : 0;
    #pragma unroll
    for (int e = 0; e < NE; e++) if (e != i0 && lg[e] > lg[i1]) i1 = e;
    float ev = expf(lg[i1] - lg[i0]);
    float w0 = 1.f / (1.f + ev);
    float w1 = ev * w0;
    wgtA[tok * 2]     = w0;
    wgtA[tok * 2 + 1] = w1;
    int p0 = atomicAdd(&counts[i0], 1);
    lists[i0 * NTOK + p0] = tok * 2;
    int p1 = atomicAdd(&counts[i1], 1);
    lists[i1 * NTOK + p1] = tok * 2 + 1;
  }
}

// ---------- gathered GEMM: 128x128 tile, BK=64, 4 waves, 16x16x32 bf16 MFMA ----------
// A rows gathered via per-expert entry lists (entry = token*2 + slot).
// L1: Hout[entry] = gelu(A_gather @ W1T^T + b1).  L2: atomicAdd(out[token], wgt*(... + b2)).
template<int KDIM, int NDIM, bool IS_L1>
__global__ __launch_bounds__(256) void moe_gemm(
    const unsigned short* __restrict__ A,
    const unsigned short* __restrict__ WT,     // [E][NDIM][KDIM] bf16
    const float* __restrict__ bias,            // [E][NDIM]
    const int* __restrict__ lists,             // [E][NTOK]
    const int* __restrict__ counts,            // [E]
    const float* __restrict__ wgtA,            // [2*NTOK]
    unsigned short* __restrict__ Hout,
    float* __restrict__ Out) {
  __shared__ unsigned short ldsA[128 * 64];
  __shared__ unsigned short ldsB[128 * 64];
  __shared__ int ldsE[128];

  const int CT    = NDIM / 128;
  const int per_e = 32 * CT;
  const int e   = blockIdx.x / per_e;
  const int rem = blockIdx.x % per_e;
  const int rt  = rem / CT;
  const int ct  = rem % CT;
  const int cnt = counts[e];
  if (rt * 128 >= cnt) return;

  const int t = threadIdx.x;
  if (t < 128) {
    int rg = rt * 128 + t;
    ldsE[t] = lists[e * NTOK + (rg < cnt ? rg : cnt - 1)];
  }
  __syncthreads();

  const int lane = t & 63;
  const int wid  = t >> 6;
  const int wr = wid >> 1, wc = wid & 1;
  const int rowsel = t >> 3, colsel = t & 7;

  const unsigned short* aptr[4];
  const unsigned short* bptr[4];
  #pragma unroll
  for (int i = 0; i < 4; i++) {
    int rl = i * 32 + rowsel;
    int entry = ldsE[rl];
    long arow = IS_L1 ? (entry >> 1) : entry;
    aptr[i] = A + arow * (long)KDIM + colsel * 8;
    bptr[i] = WT + ((long)e * NDIM + ct * 128 + rl) * KDIM + colsel * 8;
  }

  f32x4 acc[4][4] = {};
  char* lA = (char*)ldsA;
  char* lB = (char*)ldsB;

  for (int kt = 0; kt < KDIM / 64; ++kt) {
    #pragma unroll
    for (int i = 0; i < 4; i++) {
      gload_lds16(aptr[i] + kt * 64, lA + i * 4096 + wid * 1024);
      gload_lds16(bptr[i] + kt * 64, lB + i * 4096 + wid * 1024);
    }
    __syncthreads();   // compiler drains vmcnt before barrier
    #pragma unroll
    for (int kk = 0; kk < 2; ++kk) {
      bf16x8 a[4], b[4];
      int ko = kk * 32 + (lane >> 4) * 8;
      #pragma unroll
      for (int m = 0; m < 4; m++)
        a[m] = *(const bf16x8*)&ldsA[(wr * 64 + m * 16 + (lane & 15)) * 64 + ko];
      #pragma unroll
      for (int n = 0; n < 4; n++)
        b[n] = *(const bf16x8*)&ldsB[(wc * 64 + n * 16 + (lane & 15)) * 64 + ko];
      #pragma unroll
      for (int m = 0; m < 4; m++)
        #pragma unroll
        for (int n = 0; n < 4; n++)
          acc[m][n] = __builtin_amdgcn_mfma_f32_16x16x32_bf16(a[m], b[n], acc[m][n], 0, 0, 0);
    }
    __syncthreads();
  }

  // epilogue: C/D mapping col=lane&15, row=(lane>>4)*4+reg (m89-verified)
  #pragma unroll
  for (int m = 0; m < 4; m++) {
    int rbase = wr * 64 + m * 16 + (lane >> 4) * 4;
    int ent[4];
    #pragma unroll
    for (int r = 0; r < 4; r++) ent[r] = ldsE[rbase + r];
    #pragma unroll
    for (int n = 0; n < 4; n++) {
      int col = ct * 128 + wc * 64 + n * 16 + (lane & 15);
      float bv = bias[e * NDIM + col];
      #pragma unroll
      for (int r = 0; r < 4; r++) {
        if (rt * 128 + rbase + r >= cnt) continue;
        float v = acc[m][n][r] + bv;
        if (IS_L1) {
          Hout[(size_t)ent[r] * NDIM + col] = f2bf(gelu_tanh(v));
        } else {
          atomicAdd(Out + (size_t)(ent[r] >> 1) * NDIM + col, v * wgtA[ent[r]]);
        }
      }
    }
  }
}

extern "C" void kernel_launch(void* const* d_in, const int* in_sizes, int n_in,
                              void* d_out, int out_size, void* d_ws, size_t ws_size,
                              hipStream_t stream) {
  const float* inp = (const float*)d_in[0];
  const float* gw  = (const float*)d_in[1];
  const float* gb  = (const float*)d_in[2];
  const float* w1  = (const float*)d_in[3];
  const float* b1  = (const float*)d_in[4];
  const float* w2  = (const float*)d_in[5];
  const float* b2  = (const float*)d_in[6];
  float* out = (float*)d_out;

  char* ws = (char*)d_ws;
  unsigned short* Xb   = (unsigned short*)(ws + 0);          //  4 MiB: [4096][512] bf16
  unsigned short* W1T  = (unsigned short*)(ws + 4194304);    // 16 MiB: [8][2048][512] bf16
  unsigned short* W2T  = (unsigned short*)(ws + 20971520);   // 16 MiB: [8][512][2048] bf16
  unsigned short* Hbuf = (unsigned short*)(ws + 37748736);   // 32 MiB: [8192][2048] bf16
  int*   lists  = (int*)  (ws + 71303168);                   // [8][4096] int
  float* wgtA   = (float*)(ws + 71434240);                   // [8192] f32
  int*   counts = (int*)  (ws + 71467008);                   // [8] int

  hipMemsetAsync(counts, 0, NE * sizeof(int), stream);
  hipMemsetAsync(out, 0, (size_t)NTOK * DM * sizeof(float), stream);

  convx_kernel<<<NTOK * DM / 8 / 256, 256, 0, stream>>>(inp, Xb, NTOK * DM / 8);
  transw_kernel<DM, HD><<<NE * (DM / 32) * (HD / 32), 256, 0, stream>>>(w1, W1T);
  transw_kernel<HD, DM><<<NE * (HD / 32) * (DM / 32), 256, 0, stream>>>(w2, W2T);
  gate_kernel<<<NTOK / 4, 256, 0, stream>>>(inp, gw, gb, lists, counts, wgtA);
  moe_gemm<DM, HD, true ><<<NE * 32 * (HD / 128), 256, 0, stream>>>(
      Xb, W1T, b1, lists, counts, wgtA, Hbuf, nullptr);
  moe_gemm<HD, DM, false><<<NE * 32 * (DM / 128), 256, 0, stream>>>(
      Hbuf, W2T, b2, lists, counts, wgtA, nullptr, out);
}

// Round 4
// 196.493 us; speedup vs baseline: 1.3976x; 1.3976x over previous
//
#include <hip/hip_runtime.h>
#include <hip/hip_bf16.h>
#include <stdint.h>

#define NTOK 4096
#define DM   512
#define HD   2048
#define NE   8

typedef __bf16 bf16x8 __attribute__((ext_vector_type(8)));
typedef float  f32x4  __attribute__((ext_vector_type(4)));

__device__ __forceinline__ unsigned short f2bf(float f) {
  unsigned int u = __float_as_uint(f);
  u += 0x7FFF + ((u >> 16) & 1);   // RTNE
  return (unsigned short)(u >> 16);
}

__device__ __forceinline__ float gelu_tanh(float x) {
  float u = 0.7978845608028654f * (x + 0.044715f * x * x * x);
  return 0.5f * x * (1.0f + tanhf(u));
}

__device__ __forceinline__ void gload_lds16(const void* g, void* l) {
  __builtin_amdgcn_global_load_lds(
      (__attribute__((address_space(1))) const void*)g,
      (__attribute__((address_space(3))) void*)l,
      16, 0, 0);
}

// ---------- X: fp32 -> bf16 ----------
__global__ __launch_bounds__(256) void convx_kernel(
    const float* __restrict__ in, unsigned short* __restrict__ out, int n8) {
  int i = blockIdx.x * 256 + threadIdx.x;
  if (i >= n8) return;
  const f32x4* p = (const f32x4*)(in + (size_t)i * 8);
  f32x4 v0 = p[0], v1 = p[1];
  union { unsigned short s[8]; uint4 u; } o;
  #pragma unroll
  for (int j = 0; j < 4; j++) { o.s[j] = f2bf(v0[j]); o.s[4 + j] = f2bf(v1[j]); }
  *(uint4*)(out + (size_t)i * 8) = o.u;
}

// ---------- W[e][K][N] fp32 -> WT[e][N][K] bf16 (tiled transpose) ----------
template<int K, int N>
__global__ __launch_bounds__(256) void transw_kernel(
    const float* __restrict__ in, unsigned short* __restrict__ out) {
  __shared__ float tile[32][33];
  const int tpe = (K / 32) * (N / 32);
  int e   = blockIdx.x / tpe;
  int rem = blockIdx.x % tpe;
  int kt  = rem / (N / 32), nt = rem % (N / 32);
  int tx  = threadIdx.x & 31, ty = threadIdx.x >> 5;
  const float* src = in + ((size_t)e * K + kt * 32) * N + (size_t)nt * 32;
  #pragma unroll
  for (int i = 0; i < 4; i++) {
    int r = ty + i * 8;
    tile[r][tx] = src[(size_t)r * N + tx];
  }
  __syncthreads();
  unsigned short* dst = out + ((size_t)e * N + nt * 32) * K + (size_t)kt * 32;
  #pragma unroll
  for (int i = 0; i < 4; i++) {
    int rr = ty + i * 8;
    dst[(size_t)rr * K + tx] = f2bf(tile[tx][rr]);
  }
}

// ---------- gate: fp32 logits, top-2, softmax weights, expert ids (NO atomics) ----------
__global__ __launch_bounds__(256) void gate_kernel(
    const float* __restrict__ inp, const float* __restrict__ gw,
    const float* __restrict__ gb, int* __restrict__ eidx,
    float* __restrict__ wgtA) {
  int tok = blockIdx.x * 4 + (threadIdx.x >> 6);
  int l   = threadIdx.x & 63;
  const float* x = inp + (size_t)tok * DM;
  float acc[NE];
  #pragma unroll
  for (int e = 0; e < NE; e++) acc[e] = 0.f;
  #pragma unroll
  for (int j = 0; j < DM / 64; j++) {
    int d = j * 64 + l;
    float xv = x[d];
    const float* g = gw + (size_t)d * NE;
    #pragma unroll
    for (int e = 0; e < NE; e++) acc[e] += xv * g[e];
  }
  #pragma unroll
  for (int off = 32; off >= 1; off >>= 1) {
    #pragma unroll
    for (int e = 0; e < NE; e++) acc[e] += __shfl_xor(acc[e], off, 64);
  }
  if (l == 0) {
    float lg[NE];
    #pragma unroll
    for (int e = 0; e < NE; e++) lg[e] = acc[e] + gb[e];
    int i0 = 0;
    #pragma unroll
    for (int e = 1; e < NE; e++) if (lg[e] > lg[i0]) i0 = e;
    int i1 = (i0 == 0) ? 1 : 0;
    #pragma unroll
    for (int e = 0; e < NE; e++) if (e != i0 && lg[e] > lg[i1]) i1 = e;
    float ev = expf(lg[i1] - lg[i0]);
    float w0 = 1.f / (1.f + ev);
    float w1 = ev * w0;
    wgtA[tok * 2]     = w0;
    wgtA[tok * 2 + 1] = w1;
    eidx[tok * 2]     = i0;
    eidx[tok * 2 + 1] = i1;
  }
}

// ---------- build per-expert entry lists: 1 block per expert, ballot prefix scan ----------
__global__ __launch_bounds__(256) void build_lists(
    const int* __restrict__ eidx,      // [2*NTOK] expert id per entry
    int* __restrict__ lists,           // [E][NTOK]
    int* __restrict__ counts) {        // [E]
  __shared__ int wsums[4];
  __shared__ int base;
  const int e = blockIdx.x;
  const int t = threadIdx.x;
  const int lane = t & 63, w = t >> 6;
  if (t == 0) base = 0;
  __syncthreads();
  for (int it = 0; it < 2 * NTOK / 256; ++it) {
    int i = it * 256 + t;
    int match = (eidx[i] == e) ? 1 : 0;
    unsigned long long b = __ballot(match);
    int wsum = __popcll(b);
    int lpre = __popcll(b & ((1ull << lane) - 1ull));
    if (lane == 0) wsums[w] = wsum;
    __syncthreads();
    int wpre = 0;
    #pragma unroll
    for (int k = 0; k < 4; k++) if (k < w) wpre += wsums[k];
    int tot = wsums[0] + wsums[1] + wsums[2] + wsums[3];
    if (match) lists[e * NTOK + base + wpre + lpre] = i;
    __syncthreads();
    if (t == 0) base += tot;
    __syncthreads();
  }
  if (t == 0) counts[e] = base;
}

// ---------- gathered GEMM: 128x128 tile, BK=64, 4 waves, 16x16x32 bf16 MFMA ----------
// A rows gathered via per-expert entry lists (entry = token*2 + slot).
// L1: Hout[entry] = gelu(A_gather @ W1T^T + b1).  L2: atomicAdd(out[token], wgt*(... + b2)).
template<int KDIM, int NDIM, bool IS_L1>
__global__ __launch_bounds__(256) void moe_gemm(
    const unsigned short* __restrict__ A,
    const unsigned short* __restrict__ WT,     // [E][NDIM][KDIM] bf16
    const float* __restrict__ bias,            // [E][NDIM]
    const int* __restrict__ lists,             // [E][NTOK]
    const int* __restrict__ counts,            // [E]
    const float* __restrict__ wgtA,            // [2*NTOK]
    unsigned short* __restrict__ Hout,
    float* __restrict__ Out) {
  __shared__ unsigned short ldsA[128 * 64];
  __shared__ unsigned short ldsB[128 * 64];
  __shared__ int ldsE[128];

  const int CT    = NDIM / 128;
  const int per_e = 32 * CT;
  const int e   = blockIdx.x / per_e;
  const int rem = blockIdx.x % per_e;
  const int rt  = rem / CT;
  const int ct  = rem % CT;
  const int cnt = counts[e];
  if (rt * 128 >= cnt) return;

  const int t = threadIdx.x;
  if (t < 128) {
    int rg = rt * 128 + t;
    ldsE[t] = lists[e * NTOK + (rg < cnt ? rg : cnt - 1)];
  }
  __syncthreads();

  const int lane = t & 63;
  const int wid  = t >> 6;
  const int wr = wid >> 1, wc = wid & 1;
  const int rowsel = t >> 3, colsel = t & 7;

  const unsigned short* aptr[4];
  const unsigned short* bptr[4];
  #pragma unroll
  for (int i = 0; i < 4; i++) {
    int rl = i * 32 + rowsel;
    int entry = ldsE[rl];
    long arow = IS_L1 ? (entry >> 1) : entry;
    aptr[i] = A + arow * (long)KDIM + colsel * 8;
    bptr[i] = WT + ((long)e * NDIM + ct * 128 + rl) * KDIM + colsel * 8;
  }

  f32x4 acc[4][4] = {};
  char* lA = (char*)ldsA;
  char* lB = (char*)ldsB;

  for (int kt = 0; kt < KDIM / 64; ++kt) {
    #pragma unroll
    for (int i = 0; i < 4; i++) {
      gload_lds16(aptr[i] + kt * 64, lA + i * 4096 + wid * 1024);
      gload_lds16(bptr[i] + kt * 64, lB + i * 4096 + wid * 1024);
    }
    __syncthreads();   // compiler drains vmcnt before barrier
    #pragma unroll
    for (int kk = 0; kk < 2; ++kk) {
      bf16x8 a[4], b[4];
      int ko = kk * 32 + (lane >> 4) * 8;
      #pragma unroll
      for (int m = 0; m < 4; m++)
        a[m] = *(const bf16x8*)&ldsA[(wr * 64 + m * 16 + (lane & 15)) * 64 + ko];
      #pragma unroll
      for (int n = 0; n < 4; n++)
        b[n] = *(const bf16x8*)&ldsB[(wc * 64 + n * 16 + (lane & 15)) * 64 + ko];
      #pragma unroll
      for (int m = 0; m < 4; m++)
        #pragma unroll
        for (int n = 0; n < 4; n++)
          acc[m][n] = __builtin_amdgcn_mfma_f32_16x16x32_bf16(a[m], b[n], acc[m][n], 0, 0, 0);
    }
    __syncthreads();
  }

  // epilogue: C/D mapping col=lane&15, row=(lane>>4)*4+reg (m89-verified)
  #pragma unroll
  for (int m = 0; m < 4; m++) {
    int rbase = wr * 64 + m * 16 + (lane >> 4) * 4;
    int ent[4];
    #pragma unroll
    for (int r = 0; r < 4; r++) ent[r] = ldsE[rbase + r];
    #pragma unroll
    for (int n = 0; n < 4; n++) {
      int col = ct * 128 + wc * 64 + n * 16 + (lane & 15);
      float bv = bias[e * NDIM + col];
      #pragma unroll
      for (int r = 0; r < 4; r++) {
        if (rt * 128 + rbase + r >= cnt) continue;
        float v = acc[m][n][r] + bv;
        if (IS_L1) {
          Hout[(size_t)ent[r] * NDIM + col] = f2bf(gelu_tanh(v));
        } else {
          atomicAdd(Out + (size_t)(ent[r] >> 1) * NDIM + col, v * wgtA[ent[r]]);
        }
      }
    }
  }
}

extern "C" void kernel_launch(void* const* d_in, const int* in_sizes, int n_in,
                              void* d_out, int out_size, void* d_ws, size_t ws_size,
                              hipStream_t stream) {
  const float* inp = (const float*)d_in[0];
  const float* gw  = (const float*)d_in[1];
  const float* gb  = (const float*)d_in[2];
  const float* w1  = (const float*)d_in[3];
  const float* b1  = (const float*)d_in[4];
  const float* w2  = (const float*)d_in[5];
  const float* b2  = (const float*)d_in[6];
  float* out = (float*)d_out;

  char* ws = (char*)d_ws;
  unsigned short* Xb   = (unsigned short*)(ws + 0);          //  4 MiB: [4096][512] bf16
  unsigned short* W1T  = (unsigned short*)(ws + 4194304);    // 16 MiB: [8][2048][512] bf16
  unsigned short* W2T  = (unsigned short*)(ws + 20971520);   // 16 MiB: [8][512][2048] bf16
  unsigned short* Hbuf = (unsigned short*)(ws + 37748736);   // 32 MiB: [8192][2048] bf16
  int*   lists  = (int*)  (ws + 71303168);                   // [8][4096] int
  float* wgtA   = (float*)(ws + 71434240);                   // [8192] f32
  int*   counts = (int*)  (ws + 71467008);                   // [8] int
  int*   eidx   = (int*)  (ws + 71467072);                   // [8192] int

  hipMemsetAsync(out, 0, (size_t)NTOK * DM * sizeof(float), stream);

  convx_kernel<<<NTOK * DM / 8 / 256, 256, 0, stream>>>(inp, Xb, NTOK * DM / 8);
  transw_kernel<DM, HD><<<NE * (DM / 32) * (HD / 32), 256, 0, stream>>>(w1, W1T);
  transw_kernel<HD, DM><<<NE * (HD / 32) * (DM / 32), 256, 0, stream>>>(w2, W2T);
  gate_kernel<<<NTOK / 4, 256, 0, stream>>>(inp, gw, gb, eidx, wgtA);
  build_lists<<<NE, 256, 0, stream>>>(eidx, lists, counts);
  moe_gemm<DM, HD, true ><<<NE * 32 * (HD / 128), 256, 0, stream>>>(
      Xb, W1T, b1, lists, counts, wgtA, Hbuf, nullptr);
  moe_gemm<HD, DM, false><<<NE * 32 * (DM / 128), 256, 0, stream>>>(
      Hbuf, W2T, b2, lists, counts, wgtA, nullptr, out);
}

// Round 5
// 180.190 us; speedup vs baseline: 1.5240x; 1.0905x over previous
//
#include <hip/hip_runtime.h>
#include <hip/hip_bf16.h>
#include <stdint.h>

#define NTOK 4096
#define DM   512
#define HD   2048
#define NE   8

typedef __bf16 bf16x8 __attribute__((ext_vector_type(8)));
typedef float  f32x4  __attribute__((ext_vector_type(4)));

__device__ __forceinline__ unsigned short f2bf(float f) {
  unsigned int u = __float_as_uint(f);
  u += 0x7FFF + ((u >> 16) & 1);   // RTNE
  return (unsigned short)(u >> 16);
}

__device__ __forceinline__ float gelu_tanh(float x) {
  float u = 0.7978845608028654f * (x + 0.044715f * x * x * x);
  return 0.5f * x * (1.0f + tanhf(u));
}

__device__ __forceinline__ void gload_lds16(const void* g, void* l) {
  __builtin_amdgcn_global_load_lds(
      (__attribute__((address_space(1))) const void*)g,
      (__attribute__((address_space(3))) void*)l,
      16, 0, 0);
}

// ---------- X: fp32 -> bf16 ----------
__global__ __launch_bounds__(256) void convx_kernel(
    const float* __restrict__ in, unsigned short* __restrict__ out, int n8) {
  int i = blockIdx.x * 256 + threadIdx.x;
  if (i >= n8) return;
  const f32x4* p = (const f32x4*)(in + (size_t)i * 8);
  f32x4 v0 = p[0], v1 = p[1];
  union { unsigned short s[8]; uint4 u; } o;
  #pragma unroll
  for (int j = 0; j < 4; j++) { o.s[j] = f2bf(v0[j]); o.s[4 + j] = f2bf(v1[j]); }
  *(uint4*)(out + (size_t)i * 8) = o.u;
}

// ---------- W[e][K][N] fp32 -> WT[e][N][K] bf16 (tiled transpose) ----------
template<int K, int N>
__global__ __launch_bounds__(256) void transw_kernel(
    const float* __restrict__ in, unsigned short* __restrict__ out) {
  __shared__ float tile[32][33];
  const int tpe = (K / 32) * (N / 32);
  int e   = blockIdx.x / tpe;
  int rem = blockIdx.x % tpe;
  int kt  = rem / (N / 32), nt = rem % (N / 32);
  int tx  = threadIdx.x & 31, ty = threadIdx.x >> 5;
  const float* src = in + ((size_t)e * K + kt * 32) * N + (size_t)nt * 32;
  #pragma unroll
  for (int i = 0; i < 4; i++) {
    int r = ty + i * 8;
    tile[r][tx] = src[(size_t)r * N + tx];
  }
  __syncthreads();
  unsigned short* dst = out + ((size_t)e * N + nt * 32) * K + (size_t)kt * 32;
  #pragma unroll
  for (int i = 0; i < 4; i++) {
    int rr = ty + i * 8;
    dst[(size_t)rr * K + tx] = f2bf(tile[tx][rr]);
  }
}

// ---------- gate: fp32 logits, top-2, softmax weights, expert ids (NO atomics) ----------
__global__ __launch_bounds__(256) void gate_kernel(
    const float* __restrict__ inp, const float* __restrict__ gw,
    const float* __restrict__ gb, int* __restrict__ eidx,
    float* __restrict__ wgtA) {
  int tok = blockIdx.x * 4 + (threadIdx.x >> 6);
  int l   = threadIdx.x & 63;
  const float* x = inp + (size_t)tok * DM;
  float acc[NE];
  #pragma unroll
  for (int e = 0; e < NE; e++) acc[e] = 0.f;
  #pragma unroll
  for (int j = 0; j < DM / 64; j++) {
    int d = j * 64 + l;
    float xv = x[d];
    const float* g = gw + (size_t)d * NE;
    #pragma unroll
    for (int e = 0; e < NE; e++) acc[e] += xv * g[e];
  }
  #pragma unroll
  for (int off = 32; off >= 1; off >>= 1) {
    #pragma unroll
    for (int e = 0; e < NE; e++) acc[e] += __shfl_xor(acc[e], off, 64);
  }
  if (l == 0) {
    float lg[NE];
    #pragma unroll
    for (int e = 0; e < NE; e++) lg[e] = acc[e] + gb[e];
    int i0 = 0;
    #pragma unroll
    for (int e = 1; e < NE; e++) if (lg[e] > lg[i0]) i0 = e;
    int i1 = (i0 == 0) ? 1 : 0;
    #pragma unroll
    for (int e = 0; e < NE; e++) if (e != i0 && lg[e] > lg[i1]) i1 = e;
    float ev = expf(lg[i1] - lg[i0]);
    float w0 = 1.f / (1.f + ev);
    float w1 = ev * w0;
    wgtA[tok * 2]     = w0;
    wgtA[tok * 2 + 1] = w1;
    eidx[tok * 2]     = i0;
    eidx[tok * 2 + 1] = i1;
  }
}

// ---------- build per-expert entry lists: 1 block per expert, ballot prefix scan ----------
__global__ __launch_bounds__(256) void build_lists(
    const int* __restrict__ eidx,      // [2*NTOK] expert id per entry
    int* __restrict__ lists,           // [E][NTOK]
    int* __restrict__ counts) {        // [E]
  __shared__ int wsums[4];
  __shared__ int base;
  const int e = blockIdx.x;
  const int t = threadIdx.x;
  const int lane = t & 63, w = t >> 6;
  if (t == 0) base = 0;
  __syncthreads();
  for (int it = 0; it < 2 * NTOK / 256; ++it) {
    int i = it * 256 + t;
    int match = (eidx[i] == e) ? 1 : 0;
    unsigned long long b = __ballot(match);
    int wsum = __popcll(b);
    int lpre = __popcll(b & ((1ull << lane) - 1ull));
    if (lane == 0) wsums[w] = wsum;
    __syncthreads();
    int wpre = 0;
    #pragma unroll
    for (int k = 0; k < 4; k++) if (k < w) wpre += wsums[k];
    int tot = wsums[0] + wsums[1] + wsums[2] + wsums[3];
    if (match) lists[e * NTOK + base + wpre + lpre] = i;
    __syncthreads();
    if (t == 0) base += tot;
    __syncthreads();
  }
  if (t == 0) counts[e] = base;
}

// ---------- gathered GEMM: 128x128 tile, BK=64, 4 waves, 16x16x32 bf16 MFMA ----------
// 2-phase double-buffered pipeline (T3-min) + T2 XOR swizzle (both sides, rule #21).
// A rows gathered via per-expert entry lists (entry = token*2 + slot).
// L1: Hout[entry] = gelu(A_gather @ W1T^T + b1).  L2: atomicAdd(out[token], wgt*(... + b2)).
template<int KDIM, int NDIM, bool IS_L1>
__global__ __launch_bounds__(256) void moe_gemm(
    const unsigned short* __restrict__ A,
    const unsigned short* __restrict__ WT,     // [E][NDIM][KDIM] bf16
    const float* __restrict__ bias,            // [E][NDIM]
    const int* __restrict__ lists,             // [E][NTOK]
    const int* __restrict__ counts,            // [E]
    const float* __restrict__ wgtA,            // [2*NTOK]
    unsigned short* __restrict__ Hout,
    float* __restrict__ Out) {
  __shared__ unsigned short ldsA0[128 * 64];
  __shared__ unsigned short ldsB0[128 * 64];
  __shared__ unsigned short ldsA1[128 * 64];
  __shared__ unsigned short ldsB1[128 * 64];
  __shared__ int ldsE[128];

  const int CT    = NDIM / 128;
  const int per_e = 32 * CT;
  const int e   = blockIdx.x / per_e;
  const int rem = blockIdx.x % per_e;
  const int rt  = rem / CT;
  const int ct  = rem % CT;
  const int cnt = counts[e];
  if (rt * 128 >= cnt) return;

  const int t = threadIdx.x;
  if (t < 128) {
    int rg = rt * 128 + t;
    ldsE[t] = lists[e * NTOK + (rg < cnt ? rg : cnt - 1)];
  }
  __syncthreads();

  const int lane = t & 63;
  const int wid  = t >> 6;
  const int wr = wid >> 1, wc = wid & 1;
  const int rowsel = t >> 3;                       // LDS row this lane stages
  const int colsel = (t & 7) ^ (rowsel & 7);       // inverse-swizzled source slot

  const unsigned short* aptr[4];
  const unsigned short* bptr[4];
  #pragma unroll
  for (int i = 0; i < 4; i++) {
    int rl = i * 32 + rowsel;
    int entry = ldsE[rl];
    long arow = IS_L1 ? (entry >> 1) : entry;
    aptr[i] = A + arow * (long)KDIM + colsel * 8;
    bptr[i] = WT + ((long)e * NDIM + ct * 128 + rl) * KDIM + colsel * 8;
  }

  f32x4 acc[4][4] = {};

  // stage K-tile KT into the given LDS halves (linear dest; source pre-swizzled)
  #define STAGE(LA, LB, KT) do {                                              \
    const int _off = (KT) * 64;                                               \
    _Pragma("unroll")                                                         \
    for (int i = 0; i < 4; i++) {                                             \
      gload_lds16(aptr[i] + _off, (char*)(LA) + i * 4096 + wid * 1024);       \
      gload_lds16(bptr[i] + _off, (char*)(LB) + i * 4096 + wid * 1024);       \
    }                                                                         \
  } while (0)

  // compute one K-tile from the given LDS halves (swizzled read addresses)
  #define COMPUTE(LA, LB) do {                                                \
    _Pragma("unroll")                                                         \
    for (int kk = 0; kk < 2; ++kk) {                                          \
      bf16x8 a[4], b[4];                                                      \
      int ko = kk * 32 + (lane >> 4) * 8;                                     \
      _Pragma("unroll")                                                       \
      for (int m = 0; m < 4; m++) {                                           \
        int ra = wr * 64 + m * 16 + (lane & 15);                              \
        a[m] = *(const bf16x8*)&(LA)[ra * 64 + (ko ^ ((ra & 7) << 3))];       \
      }                                                                       \
      _Pragma("unroll")                                                       \
      for (int n = 0; n < 4; n++) {                                           \
        int rb = wc * 64 + n * 16 + (lane & 15);                              \
        b[n] = *(const bf16x8*)&(LB)[rb * 64 + (ko ^ ((rb & 7) << 3))];       \
      }                                                                       \
      _Pragma("unroll")                                                       \
      for (int m = 0; m < 4; m++)                                             \
        _Pragma("unroll")                                                     \
        for (int n = 0; n < 4; n++)                                           \
          acc[m][n] = __builtin_amdgcn_mfma_f32_16x16x32_bf16(                \
              a[m], b[n], acc[m][n], 0, 0, 0);                                \
    }                                                                         \
  } while (0)

  const int NKT = KDIM / 64;                       // 8 (L1) or 32 (L2), even
  STAGE(ldsA0, ldsB0, 0);
  __syncthreads();                                 // drain prologue stage
  for (int kt = 0; kt < NKT; kt += 2) {
    if (kt + 1 < NKT) STAGE(ldsA1, ldsB1, kt + 1); // prefetch next tile
    COMPUTE(ldsA0, ldsB0);                         // compute current (overlaps)
    __syncthreads();                               // drain stage of kt+1
    if (kt + 2 < NKT) STAGE(ldsA0, ldsB0, kt + 2);
    COMPUTE(ldsA1, ldsB1);
    __syncthreads();
  }
  #undef STAGE
  #undef COMPUTE

  // epilogue: C/D mapping col=lane&15, row=(lane>>4)*4+reg (m89-verified)
  #pragma unroll
  for (int m = 0; m < 4; m++) {
    int rbase = wr * 64 + m * 16 + (lane >> 4) * 4;
    int ent[4];
    #pragma unroll
    for (int r = 0; r < 4; r++) ent[r] = ldsE[rbase + r];
    #pragma unroll
    for (int n = 0; n < 4; n++) {
      int col = ct * 128 + wc * 64 + n * 16 + (lane & 15);
      float bv = bias[e * NDIM + col];
      #pragma unroll
      for (int r = 0; r < 4; r++) {
        if (rt * 128 + rbase + r >= cnt) continue;
        float v = acc[m][n][r] + bv;
        if (IS_L1) {
          Hout[(size_t)ent[r] * NDIM + col] = f2bf(gelu_tanh(v));
        } else {
          atomicAdd(Out + (size_t)(ent[r] >> 1) * NDIM + col, v * wgtA[ent[r]]);
        }
      }
    }
  }
}

extern "C" void kernel_launch(void* const* d_in, const int* in_sizes, int n_in,
                              void* d_out, int out_size, void* d_ws, size_t ws_size,
                              hipStream_t stream) {
  const float* inp = (const float*)d_in[0];
  const float* gw  = (const float*)d_in[1];
  const float* gb  = (const float*)d_in[2];
  const float* w1  = (const float*)d_in[3];
  const float* b1  = (const float*)d_in[4];
  const float* w2  = (const float*)d_in[5];
  const float* b2  = (const float*)d_in[6];
  float* out = (float*)d_out;

  char* ws = (char*)d_ws;
  unsigned short* Xb   = (unsigned short*)(ws + 0);          //  4 MiB: [4096][512] bf16
  unsigned short* W1T  = (unsigned short*)(ws + 4194304);    // 16 MiB: [8][2048][512] bf16
  unsigned short* W2T  = (unsigned short*)(ws + 20971520);   // 16 MiB: [8][512][2048] bf16
  unsigned short* Hbuf = (unsigned short*)(ws + 37748736);   // 32 MiB: [8192][2048] bf16
  int*   lists  = (int*)  (ws + 71303168);                   // [8][4096] int
  float* wgtA   = (float*)(ws + 71434240);                   // [8192] f32
  int*   counts = (int*)  (ws + 71467008);                   // [8] int
  int*   eidx   = (int*)  (ws + 71467072);                   // [8192] int

  hipMemsetAsync(out, 0, (size_t)NTOK * DM * sizeof(float), stream);

  convx_kernel<<<NTOK * DM / 8 / 256, 256, 0, stream>>>(inp, Xb, NTOK * DM / 8);
  transw_kernel<DM, HD><<<NE * (DM / 32) * (HD / 32), 256, 0, stream>>>(w1, W1T);
  transw_kernel<HD, DM><<<NE * (HD / 32) * (DM / 32), 256, 0, stream>>>(w2, W2T);
  gate_kernel<<<NTOK / 4, 256, 0, stream>>>(inp, gw, gb, eidx, wgtA);
  build_lists<<<NE, 256, 0, stream>>>(eidx, lists, counts);
  moe_gemm<DM, HD, true ><<<NE * 32 * (HD / 128), 256, 0, stream>>>(
      Xb, W1T, b1, lists, counts, wgtA, Hbuf, nullptr);
  moe_gemm<HD, DM, false><<<NE * 32 * (DM / 128), 256, 0, stream>>>(
      Hbuf, W2T, b2, lists, counts, wgtA, nullptr, out);
}